// Round 15
// baseline (170.683 us; speedup 1.0000x reference)
//
#include <hip/hip_runtime.h>
#include <hip/hip_bf16.h>
#include <math.h>

#define T_    1024
#define HID_  2048
#define NH    16
#define NKV   4
#define DH    128
#define TOPK_ 256
#define HI_   4
#define DI_   32
#define NPROJ 3072          // q(2048) + k(512) + v(512)
#define NIDX  164           // qi(128) + wi(4) + ki(32)
#define KSPLIT 8
#define KCHUNK 256

#ifndef INFINITY
#define INFINITY (__builtin_inff())
#endif

typedef __attribute__((ext_vector_type(8))) short bf16x8;
typedef __attribute__((ext_vector_type(4))) float f32x4;

__device__ inline unsigned int packbf(float f) {   // RNE f32->bf16 (bits in low 16)
    unsigned int u = __float_as_uint(f);
    return (u + 0x7fffu + ((u >> 16) & 1u)) >> 16;
}

#define GLDS16(g, l) __builtin_amdgcn_global_load_lds( \
    (const __attribute__((address_space(1))) void*)(g), \
    (__attribute__((address_space(3))) void*)(l), 16, 0, 0)

// ---------------- shared device bodies ----------------
__device__ inline void tcast_body(const float* __restrict__ W, unsigned short* __restrict__ Wt,
                                  int N, int bx, int by, int tid, float (*tile)[33]) {
    const int n0 = bx * 32, k0 = by * 32;
    const int tx = tid & 31, ty = tid >> 5;
#pragma unroll
    for (int i = 0; i < 4; ++i)
        tile[ty + i * 8][tx] = W[(size_t)(k0 + ty + i * 8) * N + (n0 + tx)];
    __syncthreads();
#pragma unroll
    for (int i = 0; i < 4; ++i) {
        int n = n0 + ty + i * 8;
        Wt[(size_t)n * HID_ + k0 + tx] = (unsigned short)packbf(tile[tx][ty + i * 8]);
    }
}

// 64x64 bf16 MFMA GEMM body, BK=64, swizzled staging (round-9 proven)
__device__ inline void gemm64_body(const unsigned short* __restrict__ A,
                                   const unsigned short* __restrict__ Bt,
                                   float* __restrict__ C, int K, int ldc,
                                   int bx, int by, int tid,
                                   unsigned short* As, unsigned short* Bs) {
    const int lane = tid & 63, w = tid >> 6;
    const int wr = w >> 1, wc = w & 1;
    const int brow = by * 64, bcol = bx * 64;
    const int l15 = lane & 15, lq = lane >> 4;

    f32x4 acc[2][2] = {};

    const int srow = tid >> 3;
    const int gsrc = ((tid & 7) ^ (srow & 7)) * 8;
    const unsigned short* ga  = A  + (size_t)(brow + srow) * K + gsrc;
    const unsigned short* ga2 = ga + (size_t)32 * K;
    const unsigned short* gb  = Bt + (size_t)(bcol + srow) * K + gsrc;
    const unsigned short* gb2 = gb + (size_t)32 * K;
    unsigned short* la  = &As[(size_t)tid * 8];
    unsigned short* la2 = &As[(size_t)(tid + 256) * 8];
    unsigned short* lb  = &Bs[(size_t)tid * 8];
    unsigned short* lb2 = &Bs[(size_t)(tid + 256) * 8];

    for (int k0 = 0; k0 < K; k0 += 64) {
        GLDS16(ga + k0,  la);
        GLDS16(ga2 + k0, la2);
        GLDS16(gb + k0,  lb);
        GLDS16(gb2 + k0, lb2);
        __syncthreads();
        bf16x8 fa[2][2], fb[2][2];
#pragma unroll
        for (int m = 0; m < 2; ++m)
#pragma unroll
            for (int kk = 0; kk < 2; ++kk) {
                int row = wr * 32 + m * 16 + l15;
                fa[m][kk] = *(const bf16x8*)&As[row * 64 + (((kk * 4 + lq) ^ (l15 & 7)) * 8)];
            }
#pragma unroll
        for (int nn = 0; nn < 2; ++nn)
#pragma unroll
            for (int kk = 0; kk < 2; ++kk) {
                int row = wc * 32 + nn * 16 + l15;
                fb[nn][kk] = *(const bf16x8*)&Bs[row * 64 + (((kk * 4 + lq) ^ (l15 & 7)) * 8)];
            }
#pragma unroll
        for (int kk = 0; kk < 2; ++kk)
#pragma unroll
            for (int m = 0; m < 2; ++m)
#pragma unroll
                for (int nn = 0; nn < 2; ++nn)
                    acc[m][nn] = __builtin_amdgcn_mfma_f32_16x16x32_bf16(fa[m][kk], fb[nn][kk], acc[m][nn], 0, 0, 0);
        __syncthreads();
    }
#pragma unroll
    for (int m = 0; m < 2; ++m)
#pragma unroll
        for (int nn = 0; nn < 2; ++nn)
#pragma unroll
            for (int q = 0; q < 4; ++q) {
                int row = brow + wr * 32 + m * 16 + lq * 4 + q;
                int col = bcol + wc * 32 + nn * 16 + l15;
                C[(size_t)row * ldc + col] = acc[m][nn][q];
            }
}

// ---------------- prep1: tcast Wq/Wk/Wv + cast_x + copy_wi ----------------
__global__ __launch_bounds__(256) void prep1(const float* __restrict__ x,
                                             const float* __restrict__ Wq,
                                             const float* __restrict__ Wk,
                                             const float* __restrict__ Wv,
                                             const float* __restrict__ Wqi,
                                             const float* __restrict__ Wwi,
                                             const float* __restrict__ Wki,
                                             unsigned short* __restrict__ xb,
                                             unsigned short* __restrict__ WtAll,
                                             float* __restrict__ Wi) {
    __shared__ float tile[32][33];
    int bid = blockIdx.x;
    const int tid = threadIdx.x;
    if (bid < 4096) { tcast_body(Wq, WtAll, HID_, bid & 63, bid >> 6, tid, tile); return; }
    bid -= 4096;
    if (bid < 1024) { tcast_body(Wk, WtAll + (size_t)2048 * HID_, 512, bid & 15, bid >> 4, tid, tile); return; }
    bid -= 1024;
    if (bid < 1024) { tcast_body(Wv, WtAll + (size_t)2560 * HID_, 512, bid & 15, bid >> 4, tid, tile); return; }
    bid -= 1024;
    if (bid < 1024) {
        int e = bid * 256 + tid;
        const float4* p = (const float4*)(x + (size_t)e * 8);
        float4 a = p[0], b = p[1];
        uint4 r;
        r.x = packbf(a.x) | (packbf(a.y) << 16);
        r.y = packbf(a.z) | (packbf(a.w) << 16);
        r.z = packbf(b.x) | (packbf(b.y) << 16);
        r.w = packbf(b.z) | (packbf(b.w) << 16);
        *(uint4*)(xb + (size_t)e * 8) = r;
        return;
    }
    bid -= 1024;
    {
        int e = bid * 256 + tid;
        if (e >= HID_ * NIDX) return;
        int k = e / NIDX, c = e - k * NIDX;
        float v;
        if (c < 128) v = Wqi[(size_t)k * 128 + c];
        else if (c < 132) v = Wwi[(size_t)k * 4 + (c - 128)];
        else v = Wki[(size_t)k * 32 + (c - 132)];
        Wi[e] = v;
    }
}

// ---------------- fusedA: bf16 proj GEMM (768) + fp32 splitk (384), LDS union ----------------
__global__ __launch_bounds__(256) void fusedA(const unsigned short* __restrict__ xb,
                                              const unsigned short* __restrict__ WtAll,
                                              float* __restrict__ proj,
                                              const float* __restrict__ x,
                                              const float* __restrict__ Wi,
                                              float* __restrict__ Cpart) {
    __shared__ __align__(16) char smem[64 * 64 * 2 * 2];   // 16384 B, unioned
    const int tid = threadIdx.x;
    int bid = blockIdx.x;

    if (bid < 768) {   // gemm64 proj: grid (48, 16)
        unsigned short* As = (unsigned short*)smem;
        unsigned short* Bs = As + 64 * 64;
        gemm64_body(xb, WtAll, proj, HID_, NPROJ, bid % 48, bid / 48, tid, As, Bs);
        return;
    }
    // splitk: grid (3, 16, 8) flattened, float4 staging
    float (*As2)[68] = (float(*)[68])smem;
    float (*Bs2)[68] = As2 + 16;
    int s = bid - 768;
    const int bx = s % 3, by = (s / 3) % 16, z = s / 48;
    const int tx = tid & 15, ty = tid >> 4;
    const int brow = by * 64, bcol = bx * 64;
    const int kbeg = z * KCHUNK, kend = kbeg + KCHUNK;
    const int M = T_, N = NIDX, K = HID_;

    const int ar = tid >> 2, ac4 = (tid & 3) * 4;
    const int br = tid >> 4, bc4 = (tid & 15) * 4;

    float acc[4][4];
#pragma unroll
    for (int i = 0; i < 4; ++i)
#pragma unroll
        for (int j = 0; j < 4; ++j) acc[i][j] = 0.f;

    for (int k0 = kbeg; k0 < kend; k0 += 16) {
        float4 va = *(const float4*)&x[(size_t)(brow + ar) * K + k0 + ac4];
        float4 vb;
        int col = bcol + bc4;
        if (col <= N - 4) vb = *(const float4*)&Wi[(size_t)(k0 + br) * N + col];
        else vb = (float4){0.f, 0.f, 0.f, 0.f};
        As2[ac4 + 0][ar] = va.x;
        As2[ac4 + 1][ar] = va.y;
        As2[ac4 + 2][ar] = va.z;
        As2[ac4 + 3][ar] = va.w;
        *(float4*)&Bs2[br][bc4] = vb;
        __syncthreads();
#pragma unroll
        for (int kk = 0; kk < 16; ++kk) {
            float4 a4 = *(const float4*)&As2[kk][ty * 4];
            float4 b4 = *(const float4*)&Bs2[kk][tx * 4];
            float a[4] = {a4.x, a4.y, a4.z, a4.w};
            float b[4] = {b4.x, b4.y, b4.z, b4.w};
#pragma unroll
            for (int i = 0; i < 4; ++i)
#pragma unroll
                for (int j = 0; j < 4; ++j) acc[i][j] += a[i] * b[j];
        }
        __syncthreads();
    }
#pragma unroll
    for (int i = 0; i < 4; ++i) {
        int r = brow + ty * 4 + i;
#pragma unroll
        for (int j = 0; j < 4; ++j) {
            int c = bcol + tx * 4 + j;
            if (c < N) Cpart[((size_t)z * M + r) * N + c] = acc[i][j];
        }
    }
}

// ---------------- reduce split-K partials; also emit dense kib ----------------
__global__ __launch_bounds__(256) void reduce_k(const float* __restrict__ Cpart,
                                                float* __restrict__ Cout,
                                                float* __restrict__ kib, int MN) {
    int e = blockIdx.x * 256 + threadIdx.x;
    if (e >= MN) return;
    float s = 0.f;
#pragma unroll
    for (int z = 0; z < KSPLIT; ++z) s += Cpart[(size_t)z * MN + e];
    Cout[e] = s;
    int t = e / NIDX, c = e - t * NIDX;
    if (c >= 132) kib[(size_t)t * DI_ + (c - 132)] = s;
}

// ---------------- fusedB: rope/rms/vcast (5376) + tcast Wo (4096) + idxtopk (1024) ----------------
__global__ __launch_bounds__(256) void fusedB(const float* __restrict__ proj,
                                              const float* __restrict__ cosb,
                                              const float* __restrict__ sinb,
                                              unsigned short* __restrict__ qbb,
                                              unsigned short* __restrict__ kbb,
                                              unsigned int* __restrict__ vbb,
                                              const float* __restrict__ Wo,
                                              unsigned short* __restrict__ Wot,
                                              const float* __restrict__ proji,
                                              const float* __restrict__ kib,
                                              int* __restrict__ idxout) {
    __shared__ float tile[32][33];
    const int tid = threadIdx.x;
    int bid = blockIdx.x;

    if (bid < 5376) {   // rope units: u = bid*4 + wave, u = t*21 + h
        const int w = tid >> 6, lane = tid & 63;
        const int u = bid * 4 + w;
        const int t = u / 21, h = u - t * 21;
        if (h < 20) {
            const float* row;
            unsigned short* dst;
            if (h < 16) { row = proj + (size_t)t * NPROJ + h * DH;               dst = qbb + ((size_t)t * NH + h) * DH; }
            else        { row = proj + (size_t)t * NPROJ + HID_ + (h - 16) * DH; dst = kbb + ((size_t)t * NKV + (h - 16)) * DH; }
            float a = row[lane], b = row[lane + 64];
            float c0 = cosb[t * DH + lane],      s0 = sinb[t * DH + lane];
            float c1 = cosb[t * DH + lane + 64], s1 = sinb[t * DH + lane + 64];
            float r0 = a * c0 - b * s0;
            float r1 = b * c1 + a * s1;
            float ss = r0 * r0 + r1 * r1;
#pragma unroll
            for (int o = 32; o > 0; o >>= 1) ss += __shfl_xor(ss, o);
            float inv = rsqrtf(ss * (1.0f / 128.0f) + 1.1920929e-07f);
            dst[lane]      = (unsigned short)packbf(r0 * inv);
            dst[lane + 64] = (unsigned short)packbf(r1 * inv);
        } else {
            const float* src = proj + (size_t)t * NPROJ + HID_ + 512;
#pragma unroll
            for (int i = 0; i < 4; ++i) {
                int c2 = lane + i * 64;
                vbb[(size_t)t * 256 + c2] = packbf(src[2 * c2]) | (packbf(src[2 * c2 + 1]) << 16);
            }
        }
        return;
    }
    bid -= 5376;
    if (bid < 4096) {   // tcast Wo -> Wot
        tcast_body(Wo, Wot, HID_, bid & 63, bid >> 6, tid, tile);
        return;
    }
    bid -= 4096;
    // ---- idxtopk: t = bid ----
    {
        const int t = bid;
        int* orow = idxout + (size_t)t * TOPK_;
        if (t < TOPK_) { orow[tid] = tid; return; }

        __shared__ float qsh[128];
        __shared__ float wsh[4];
        if (tid < 128) qsh[tid] = proji[(size_t)t * NIDX + tid];
        else if (tid < 132) wsh[tid - 128] = proji[(size_t)t * NIDX + tid];
        __syncthreads();

        const int n = t + 1;
        const int lane = tid & 63, wave = tid >> 6;

        unsigned int key[4];
#pragma unroll
        for (int j = 0; j < 4; ++j) {
            int s = j * 256 + tid;
            if (s < n) {
                const float4* kr = (const float4*)&kib[(size_t)s * DI_];
                float4 k4[8];
#pragma unroll
                for (int d4 = 0; d4 < 8; ++d4) k4[d4] = kr[d4];
                float sc = 0.f;
#pragma unroll
                for (int h = 0; h < HI_; ++h) {
                    float d = 0.f;
#pragma unroll
                    for (int d4 = 0; d4 < 8; ++d4) {
                        const float* qp = &qsh[h * 32 + d4 * 4];
                        d += k4[d4].x * qp[0] + k4[d4].y * qp[1] +
                             k4[d4].z * qp[2] + k4[d4].w * qp[3];
                    }
                    sc += wsh[h] * fmaxf(d, 0.f);
                }
                unsigned int u = __float_as_uint(sc);
                key[j] = (u & 0x80000000u) ? ~u : (u | 0x80000000u);
            } else key[j] = 0u;
        }

        __shared__ int wcnt[2][4];
        unsigned int prefix = 0;
#pragma unroll 1
        for (int b = 31; b >= 0; --b) {
            unsigned int cand = prefix | (1u << b);
            int c = (key[0] >= cand) + (key[1] >= cand) + (key[2] >= cand) + (key[3] >= cand);
#pragma unroll
            for (int o = 32; o > 0; o >>= 1) c += __shfl_xor(c, o);
            if (lane == 0) wcnt[b & 1][wave] = c;
            __syncthreads();
            int total = wcnt[b & 1][0] + wcnt[b & 1][1] + wcnt[b & 1][2] + wcnt[b & 1][3];
            if (total >= TOPK_) prefix = cand;
        }
        const unsigned int T = prefix;

        __shared__ int posc;
        __shared__ int eqtot[4][4];
        __syncthreads();
        {
            int c = (key[0] > T) + (key[1] > T) + (key[2] > T) + (key[3] > T);
#pragma unroll
            for (int o = 32; o > 0; o >>= 1) c += __shfl_xor(c, o);
            if (lane == 0) wcnt[0][wave] = c;
        }
        if (tid == 0) posc = 0;

        int e[4]; int myp[4];
#pragma unroll
        for (int j = 0; j < 4; ++j) {
            e[j] = (key[j] == T) ? 1 : 0;
            unsigned long long m = __ballot(e[j]);
            myp[j] = __popcll(m & ((1ull << lane) - 1ull));
            if (lane == 0) eqtot[j][wave] = __popcll(m);
        }
        __syncthreads();
        const int cntGT = wcnt[0][0] + wcnt[0][1] + wcnt[0][2] + wcnt[0][3];
        const int need = TOPK_ - cntGT;

#pragma unroll
        for (int j = 0; j < 4; ++j)
            if (key[j] > T) {
                int p = atomicAdd(&posc, 1);
                orow[p] = j * 256 + tid;
            }
        int runbase = 0;
#pragma unroll
        for (int j = 0; j < 4; ++j) {
            int wavebase = 0;
#pragma unroll
            for (int w2 = 0; w2 < 4; ++w2) if (w2 < wave) wavebase += eqtot[j][w2];
            int g = runbase + wavebase + myp[j];
            if (e[j] && g < need) orow[cntGT + g] = j * 256 + tid;
            runbase += eqtot[j][0] + eqtot[j][1] + eqtot[j][2] + eqtot[j][3];
        }
    }
}

// ---------------- standalone 64x64 GEMM (Wo output projection) ----------------
__global__ __launch_bounds__(256) void gemm64(const unsigned short* __restrict__ A,
                                              const unsigned short* __restrict__ Bt,
                                              float* __restrict__ C,
                                              int K, int ldc) {
    __shared__ unsigned short As[64 * 64];
    __shared__ unsigned short Bs[64 * 64];
    gemm64_body(A, Bt, C, K, ldc, blockIdx.x, blockIdx.y, threadIdx.x, As, Bs);
}

// ---------------- MFMA sparse GQA v7: 32-token dbuf tiles (~24.5 KB LDS) ----------------
__global__ __launch_bounds__(256) void attn7(const unsigned short* __restrict__ qbb,
                                             const unsigned short* __restrict__ kbb,
                                             const unsigned short* __restrict__ vbb,
                                             const int* __restrict__ idx,
                                             unsigned short* __restrict__ attnb) {
    const int t = blockIdx.x, n = blockIdx.y;
    const int tid = threadIdx.x, lane = tid & 63, w = tid >> 6;
    const int C = (t + 1 < TOPK_) ? t + 1 : TOPK_;
    const int l15 = lane & 15, lq = lane >> 4;

    __shared__ int sidx[TOPK_];
    __shared__ float sp[4][TOPK_];
    __shared__ float sinv[4];
    __shared__ unsigned short P[4][264];
    __shared__ unsigned short Vs[2][32 * 128];   // 32-token tiles, double-buffered

    sidx[tid] = idx[(size_t)t * TOPK_ + tid];
    __syncthreads();

    // stage one 32-token tile: 512 chunks of 16B; thread handles chunks tid, tid+256
#define STAGE_V(buf, tau)                                                          \
    {                                                                              \
        _Pragma("unroll")                                                          \
        for (int it = 0; it < 2; ++it) {                                           \
            int c = tid + it * 256;                                                \
            int r = c >> 4, doff = (c & 15) * 8;                                   \
            int gs = doff ^ (((r >> 3) & 3) << 4);                                 \
            GLDS16(&vbb[((size_t)sidx[(tau) * 32 + r] * NKV + n) * DH + gs],       \
                   &Vs[buf][(size_t)c * 8]);                                       \
        }                                                                          \
    }

    STAGE_V(0, 0);   // latency hidden under QK^T + softmax

    const size_t qrow = (size_t)t * NH + n * 4 + (l15 < 4 ? l15 : 3);
    bf16x8 qf[4];
#pragma unroll
    for (int ks = 0; ks < 4; ++ks)
        qf[ks] = *(const bf16x8*)&qbb[qrow * DH + ks * 32 + lq * 8];

    // ---- QK^T: wave w -> token tiles w*4 .. w*4+3 (K gathered direct from L2)
#pragma unroll
    for (int tt = 0; tt < 4; ++tt) {
        const int tile = w * 4 + tt;
        const int tok = tile * 16 + l15;
        const unsigned short* krow = &kbb[((size_t)sidx[tok] * NKV + n) * DH];
        f32x4 acc = {0.f, 0.f, 0.f, 0.f};
        __builtin_amdgcn_s_setprio(1);
#pragma unroll
        for (int ks = 0; ks < 4; ++ks) {
            bf16x8 yf = *(const bf16x8*)&krow[ks * 32 + lq * 8];
            acc = __builtin_amdgcn_mfma_f32_16x16x32_bf16(qf[ks], yf, acc, 0, 0, 0);
        }
        __builtin_amdgcn_s_setprio(0);
        if (lane < 16) {
            int j = tile * 16 + lane;
            bool ok = j < C;
#pragma unroll
            for (int q = 0; q < 4; ++q)
                sp[q][j] = ok ? acc[q] * 0.08838834764831845f : -INFINITY;
        }
    }
    __syncthreads();

    // ---- softmax: wave w -> head w
    {
        float v0 = sp[w][lane], v1 = sp[w][lane + 64],
              v2 = sp[w][lane + 128], v3 = sp[w][lane + 192];
        float m = fmaxf(fmaxf(v0, v1), fmaxf(v2, v3));
#pragma unroll
        for (int o = 32; o > 0; o >>= 1) m = fmaxf(m, __shfl_xor(m, o));
        float e0 = expf(v0 - m), e1 = expf(v1 - m), e2 = expf(v2 - m), e3 = expf(v3 - m);
        float sum = e0 + e1 + e2 + e3;
#pragma unroll
        for (int o = 32; o > 0; o >>= 1) sum += __shfl_xor(sum, o);
        if (lane == 0) sinv[w] = 1.f / sum;
        P[w][lane]       = (unsigned short)packbf(e0);
        P[w][lane + 64]  = (unsigned short)packbf(e1);
        P[w][lane + 128] = (unsigned short)packbf(e2);
        P[w][lane + 192] = (unsigned short)packbf(e3);
    }
    __syncthreads();   // P visible; V tile 0 drained (QK phase covered it)

    // ---- PV: 8 taus of 32 tokens; ping-pong; 1 barrier/tau
    const int prow = (l15 < 4) ? l15 : 3;
    f32x4 pacc[2] = {};
#pragma unroll
    for (int tau = 0; tau < 8; ++tau) {
        const unsigned short* Vb = Vs[tau & 1];
        if (tau < 7) STAGE_V((tau + 1) & 1, tau + 1);
        bf16x8 xf = *(const bf16x8*)&P[prow][tau * 32 + lq * 8];
        const int colr0 = ((2 * w + 0) * 16 + l15) ^ (lq << 4);
        const int colr1 = ((2 * w + 1) * 16 + l15) ^ (lq << 4);
        bf16x8 yf0, yf1;
#pragma unroll
        for (int j = 0; j < 8; ++j) {
            yf0[j] = (short)Vb[(lq * 8 + j) * 128 + colr0];
            yf1[j] = (short)Vb[(lq * 8 + j) * 128 + colr1];
        }
        __builtin_amdgcn_s_setprio(1);
        pacc[0] = __builtin_amdgcn_mfma_f32_16x16x32_bf16(xf, yf0, pacc[0], 0, 0, 0);
        pacc[1] = __builtin_amdgcn_mfma_f32_16x16x32_bf16(xf, yf1, pacc[1], 0, 0, 0);
        __builtin_amdgcn_s_setprio(0);
        __syncthreads();   // drains tau+1 loads + fences buffer reuse
    }
#undef STAGE_V

    if (lane < 16) {
#pragma unroll
        for (int dt = 0; dt < 2; ++dt)
#pragma unroll
            for (int q = 0; q < 4; ++q)
                attnb[(size_t)(t * NH + n * 4 + q) * DH + (2 * w + dt) * 16 + l15] =
                    (unsigned short)packbf(pacc[dt][q] * sinv[q]);
    }
}

// ---------------- launch ----------------
extern "C" void kernel_launch(void* const* d_in, const int* in_sizes, int n_in,
                              void* d_out, int out_size, void* d_ws, size_t ws_size,
                              hipStream_t stream) {
    const float* x    = (const float*)d_in[0];
    const float* cosb = (const float*)d_in[1];
    const float* sinb = (const float*)d_in[2];
    const float* Wq   = (const float*)d_in[3];
    const float* Wk   = (const float*)d_in[4];
    const float* Wv   = (const float*)d_in[5];
    const float* Wo   = (const float*)d_in[6];
    const float* Wqi  = (const float*)d_in[7];
    const float* Wwi  = (const float*)d_in[8];
    const float* Wki  = (const float*)d_in[9];
    float* out = (float*)d_out;

    unsigned short* xb    = (unsigned short*)d_ws;             // 1024*2048 bf16
    unsigned short* WtAll = xb + 2097152;                      // 3072*2048 bf16
    float*  proj  = (float*)(WtAll + 6291456);                 // 1024*3072 f32
    float*  Wi    = proj + 3145728;                            // 2048*164 f32
    float*  proji = Wi + 335872;                               // 1024*164 f32
    float*  kib   = proji + 167936;                            // 1024*32 f32 (4MB slot)
    int*    idxb  = (int*)(kib + 1048576);                     // 1024*256 int
    unsigned short* kbb   = (unsigned short*)(idxb + 262144);  // 1024*512 bf16
    unsigned short* vbb   = kbb + 524288;                      // 1024*512 bf16
    unsigned short* attnb = vbb + 524288;                      // 1024*2048 bf16
    unsigned short* Wot   = WtAll;     // reuse after proj GEMM
    unsigned short* qbb   = xb;        // reuse after proj GEMM
    float* Cpart = (float*)kbb;        // split-K partials, dead before kbb written

    // 1) prep: tcast Wq/Wk/Wv + cast_x + copy_wi
    prep1<<<dim3(8480), dim3(256), 0, stream>>>(x, Wq, Wk, Wv, Wqi, Wwi, Wki, xb, WtAll, Wi);

    // 2) fusedA: bf16 proj GEMM (768) + fp32 indexer splitk (384)
    fusedA<<<dim3(1152), dim3(256), 0, stream>>>(xb, WtAll, proj, x, Wi, Cpart);

    // 3) reduce split-K partials -> proji, kib
    reduce_k<<<dim3((T_ * NIDX + 255) / 256), dim3(256), 0, stream>>>(Cpart, proji, kib, T_ * NIDX);

    // 4) fusedB: rope/rms q,k + v cast (5376) + tcast Wo (4096) + idxtopk (1024)
    fusedB<<<dim3(10496), dim3(256), 0, stream>>>(proj, cosb, sinb, qbb, kbb, (unsigned int*)vbb,
                                                  Wo, Wot, proji, kib, idxb);

    // 5) sparse attention (32-token dbuf tiles)
    attn7<<<dim3(T_, NKV), dim3(256), 0, stream>>>(qbb, kbb, vbb, idxb, attnb);

    // 6) output projection
    gemm64<<<dim3(HID_ / 64, T_ / 64), dim3(256), 0, stream>>>(attnb, Wot, out, HID_, HID_);
}

// Round 16
// 169.421 us; speedup vs baseline: 1.0074x; 1.0074x over previous
//
#include <hip/hip_runtime.h>
#include <hip/hip_bf16.h>
#include <math.h>

#define T_    1024
#define HID_  2048
#define NH    16
#define NKV   4
#define DH    128
#define TOPK_ 256
#define HI_   4
#define DI_   32
#define NPROJ 3072          // q(2048) + k(512) + v(512)
#define NIDX  164           // qi(128) + wi(4) + ki(32)
#define KSPLIT 8
#define KCHUNK 256

#ifndef INFINITY
#define INFINITY (__builtin_inff())
#endif

typedef __attribute__((ext_vector_type(8))) short bf16x8;
typedef __attribute__((ext_vector_type(4))) float f32x4;

__device__ inline unsigned int packbf(float f) {   // RNE f32->bf16 (bits in low 16)
    unsigned int u = __float_as_uint(f);
    return (u + 0x7fffu + ((u >> 16) & 1u)) >> 16;
}

#define GLDS16(g, l) __builtin_amdgcn_global_load_lds( \
    (const __attribute__((address_space(1))) void*)(g), \
    (__attribute__((address_space(3))) void*)(l), 16, 0, 0)

// ---------------- shared device bodies ----------------
__device__ inline void tcast_body(const float* __restrict__ W, unsigned short* __restrict__ Wt,
                                  int N, int bx, int by, int tid, float (*tile)[33]) {
    const int n0 = bx * 32, k0 = by * 32;
    const int tx = tid & 31, ty = tid >> 5;
#pragma unroll
    for (int i = 0; i < 4; ++i)
        tile[ty + i * 8][tx] = W[(size_t)(k0 + ty + i * 8) * N + (n0 + tx)];
    __syncthreads();
#pragma unroll
    for (int i = 0; i < 4; ++i) {
        int n = n0 + ty + i * 8;
        Wt[(size_t)n * HID_ + k0 + tx] = (unsigned short)packbf(tile[tx][ty + i * 8]);
    }
}

// 64x64 bf16 MFMA GEMM body, BK=64, swizzled staging + T3 2-phase pipeline.
// As/Bs are DOUBLE buffers: 2 x 64x64 ushorts each (8192 elems).
// Schedule: prologue STAGE(0); barrier; loop { STAGE(next); COMPUTE(cur); barrier }.
// __syncthreads drains vmcnt(0) -> next-tile loads fly across the whole compute phase.
__device__ inline void gemm64_body(const unsigned short* __restrict__ A,
                                   const unsigned short* __restrict__ Bt,
                                   float* __restrict__ C, int K, int ldc,
                                   int bx, int by, int tid,
                                   unsigned short* As, unsigned short* Bs) {
    const int lane = tid & 63, w = tid >> 6;
    const int wr = w >> 1, wc = w & 1;
    const int brow = by * 64, bcol = bx * 64;
    const int l15 = lane & 15, lq = lane >> 4;

    f32x4 acc[2][2] = {};

    const int srow = tid >> 3;
    const int gsrc = ((tid & 7) ^ (srow & 7)) * 8;
    const unsigned short* ga  = A  + (size_t)(brow + srow) * K + gsrc;
    const unsigned short* ga2 = ga + (size_t)32 * K;
    const unsigned short* gb  = Bt + (size_t)(bcol + srow) * K + gsrc;
    const unsigned short* gb2 = gb + (size_t)32 * K;
    const int lo1 = tid * 8, lo2 = (tid + 256) * 8;

    // prologue: stage tile 0 into buffer 0
    GLDS16(ga,  &As[lo1]);
    GLDS16(ga2, &As[lo2]);
    GLDS16(gb,  &Bs[lo1]);
    GLDS16(gb2, &Bs[lo2]);
    __syncthreads();

    const int NT = K >> 6;
    for (int kt = 0; kt < NT; ++kt) {
        const int cur = (kt & 1) * 4096;
        if (kt + 1 < NT) {                 // issue next tile into the other buffer
            const int nxt = ((kt + 1) & 1) * 4096;
            const int k0 = (kt + 1) << 6;
            GLDS16(ga + k0,  &As[nxt + lo1]);
            GLDS16(ga2 + k0, &As[nxt + lo2]);
            GLDS16(gb + k0,  &Bs[nxt + lo1]);
            GLDS16(gb2 + k0, &Bs[nxt + lo2]);
        }
        const unsigned short* Ac = &As[cur];
        const unsigned short* Bc = &Bs[cur];
        bf16x8 fa[2][2], fb[2][2];
#pragma unroll
        for (int m = 0; m < 2; ++m)
#pragma unroll
            for (int kk = 0; kk < 2; ++kk) {
                int row = wr * 32 + m * 16 + l15;
                fa[m][kk] = *(const bf16x8*)&Ac[row * 64 + (((kk * 4 + lq) ^ (l15 & 7)) * 8)];
            }
#pragma unroll
        for (int nn = 0; nn < 2; ++nn)
#pragma unroll
            for (int kk = 0; kk < 2; ++kk) {
                int row = wc * 32 + nn * 16 + l15;
                fb[nn][kk] = *(const bf16x8*)&Bc[row * 64 + (((kk * 4 + lq) ^ (l15 & 7)) * 8)];
            }
#pragma unroll
        for (int kk = 0; kk < 2; ++kk)
#pragma unroll
            for (int m = 0; m < 2; ++m)
#pragma unroll
                for (int nn = 0; nn < 2; ++nn)
                    acc[m][nn] = __builtin_amdgcn_mfma_f32_16x16x32_bf16(fa[m][kk], fb[nn][kk], acc[m][nn], 0, 0, 0);
        __syncthreads();   // drains next-tile glds (flew over compute) + fences buffer reuse
    }
#pragma unroll
    for (int m = 0; m < 2; ++m)
#pragma unroll
        for (int nn = 0; nn < 2; ++nn)
#pragma unroll
            for (int q = 0; q < 4; ++q) {
                int row = brow + wr * 32 + m * 16 + lq * 4 + q;
                int col = bcol + wc * 32 + nn * 16 + l15;
                C[(size_t)row * ldc + col] = acc[m][nn][q];
            }
}

// ---------------- prep1: tcast Wq/Wk/Wv + cast_x + copy_wi ----------------
__global__ __launch_bounds__(256) void prep1(const float* __restrict__ x,
                                             const float* __restrict__ Wq,
                                             const float* __restrict__ Wk,
                                             const float* __restrict__ Wv,
                                             const float* __restrict__ Wqi,
                                             const float* __restrict__ Wwi,
                                             const float* __restrict__ Wki,
                                             unsigned short* __restrict__ xb,
                                             unsigned short* __restrict__ WtAll,
                                             float* __restrict__ Wi) {
    __shared__ float tile[32][33];
    int bid = blockIdx.x;
    const int tid = threadIdx.x;
    if (bid < 4096) { tcast_body(Wq, WtAll, HID_, bid & 63, bid >> 6, tid, tile); return; }
    bid -= 4096;
    if (bid < 1024) { tcast_body(Wk, WtAll + (size_t)2048 * HID_, 512, bid & 15, bid >> 4, tid, tile); return; }
    bid -= 1024;
    if (bid < 1024) { tcast_body(Wv, WtAll + (size_t)2560 * HID_, 512, bid & 15, bid >> 4, tid, tile); return; }
    bid -= 1024;
    if (bid < 1024) {
        int e = bid * 256 + tid;
        const float4* p = (const float4*)(x + (size_t)e * 8);
        float4 a = p[0], b = p[1];
        uint4 r;
        r.x = packbf(a.x) | (packbf(a.y) << 16);
        r.y = packbf(a.z) | (packbf(a.w) << 16);
        r.z = packbf(b.x) | (packbf(b.y) << 16);
        r.w = packbf(b.z) | (packbf(b.w) << 16);
        *(uint4*)(xb + (size_t)e * 8) = r;
        return;
    }
    bid -= 1024;
    {
        int e = bid * 256 + tid;
        if (e >= HID_ * NIDX) return;
        int k = e / NIDX, c = e - k * NIDX;
        float v;
        if (c < 128) v = Wqi[(size_t)k * 128 + c];
        else if (c < 132) v = Wwi[(size_t)k * 4 + (c - 128)];
        else v = Wki[(size_t)k * 32 + (c - 132)];
        Wi[e] = v;
    }
}

// ---------------- fusedA: bf16 proj GEMM (768) + fp32 splitk (384), LDS union ----------------
__global__ __launch_bounds__(256) void fusedA(const unsigned short* __restrict__ xb,
                                              const unsigned short* __restrict__ WtAll,
                                              float* __restrict__ proj,
                                              const float* __restrict__ x,
                                              const float* __restrict__ Wi,
                                              float* __restrict__ Cpart) {
    __shared__ __align__(16) char smem[64 * 64 * 2 * 2 * 2];   // 32768 B (dbuf gemm) unioned
    const int tid = threadIdx.x;
    int bid = blockIdx.x;

    if (bid < 768) {   // gemm64 proj: grid (48, 16)
        unsigned short* As = (unsigned short*)smem;            // 2 x 4096
        unsigned short* Bs = As + 8192;
        gemm64_body(xb, WtAll, proj, HID_, NPROJ, bid % 48, bid / 48, tid, As, Bs);
        return;
    }
    // splitk: grid (3, 16, 8) flattened, float4 staging
    float (*As2)[68] = (float(*)[68])smem;
    float (*Bs2)[68] = As2 + 16;
    int s = bid - 768;
    const int bx = s % 3, by = (s / 3) % 16, z = s / 48;
    const int tx = tid & 15, ty = tid >> 4;
    const int brow = by * 64, bcol = bx * 64;
    const int kbeg = z * KCHUNK, kend = kbeg + KCHUNK;
    const int M = T_, N = NIDX, K = HID_;

    const int ar = tid >> 2, ac4 = (tid & 3) * 4;
    const int br = tid >> 4, bc4 = (tid & 15) * 4;

    float acc[4][4];
#pragma unroll
    for (int i = 0; i < 4; ++i)
#pragma unroll
        for (int j = 0; j < 4; ++j) acc[i][j] = 0.f;

    for (int k0 = kbeg; k0 < kend; k0 += 16) {
        float4 va = *(const float4*)&x[(size_t)(brow + ar) * K + k0 + ac4];
        float4 vb;
        int col = bcol + bc4;
        if (col <= N - 4) vb = *(const float4*)&Wi[(size_t)(k0 + br) * N + col];
        else vb = (float4){0.f, 0.f, 0.f, 0.f};
        As2[ac4 + 0][ar] = va.x;
        As2[ac4 + 1][ar] = va.y;
        As2[ac4 + 2][ar] = va.z;
        As2[ac4 + 3][ar] = va.w;
        *(float4*)&Bs2[br][bc4] = vb;
        __syncthreads();
#pragma unroll
        for (int kk = 0; kk < 16; ++kk) {
            float4 a4 = *(const float4*)&As2[kk][ty * 4];
            float4 b4 = *(const float4*)&Bs2[kk][tx * 4];
            float a[4] = {a4.x, a4.y, a4.z, a4.w};
            float b[4] = {b4.x, b4.y, b4.z, b4.w};
#pragma unroll
            for (int i = 0; i < 4; ++i)
#pragma unroll
                for (int j = 0; j < 4; ++j) acc[i][j] += a[i] * b[j];
        }
        __syncthreads();
    }
#pragma unroll
    for (int i = 0; i < 4; ++i) {
        int r = brow + ty * 4 + i;
#pragma unroll
        for (int j = 0; j < 4; ++j) {
            int c = bcol + tx * 4 + j;
            if (c < N) Cpart[((size_t)z * M + r) * N + c] = acc[i][j];
        }
    }
}

// ---------------- reduce split-K partials; also emit dense kib ----------------
__global__ __launch_bounds__(256) void reduce_k(const float* __restrict__ Cpart,
                                                float* __restrict__ Cout,
                                                float* __restrict__ kib, int MN) {
    int e = blockIdx.x * 256 + threadIdx.x;
    if (e >= MN) return;
    float s = 0.f;
#pragma unroll
    for (int z = 0; z < KSPLIT; ++z) s += Cpart[(size_t)z * MN + e];
    Cout[e] = s;
    int t = e / NIDX, c = e - t * NIDX;
    if (c >= 132) kib[(size_t)t * DI_ + (c - 132)] = s;
}

// ---------------- fusedB: rope/rms/vcast (5376) + tcast Wo (4096) + idxtopk (1024) ----------------
__global__ __launch_bounds__(256) void fusedB(const float* __restrict__ proj,
                                              const float* __restrict__ cosb,
                                              const float* __restrict__ sinb,
                                              unsigned short* __restrict__ qbb,
                                              unsigned short* __restrict__ kbb,
                                              unsigned int* __restrict__ vbb,
                                              const float* __restrict__ Wo,
                                              unsigned short* __restrict__ Wot,
                                              const float* __restrict__ proji,
                                              const float* __restrict__ kib,
                                              int* __restrict__ idxout) {
    __shared__ float tile[32][33];
    const int tid = threadIdx.x;
    int bid = blockIdx.x;

    if (bid < 5376) {   // rope units: u = bid*4 + wave, u = t*21 + h
        const int w = tid >> 6, lane = tid & 63;
        const int u = bid * 4 + w;
        const int t = u / 21, h = u - t * 21;
        if (h < 20) {
            const float* row;
            unsigned short* dst;
            if (h < 16) { row = proj + (size_t)t * NPROJ + h * DH;               dst = qbb + ((size_t)t * NH + h) * DH; }
            else        { row = proj + (size_t)t * NPROJ + HID_ + (h - 16) * DH; dst = kbb + ((size_t)t * NKV + (h - 16)) * DH; }
            float a = row[lane], b = row[lane + 64];
            float c0 = cosb[t * DH + lane],      s0 = sinb[t * DH + lane];
            float c1 = cosb[t * DH + lane + 64], s1 = sinb[t * DH + lane + 64];
            float r0 = a * c0 - b * s0;
            float r1 = b * c1 + a * s1;
            float ss = r0 * r0 + r1 * r1;
#pragma unroll
            for (int o = 32; o > 0; o >>= 1) ss += __shfl_xor(ss, o);
            float inv = rsqrtf(ss * (1.0f / 128.0f) + 1.1920929e-07f);
            dst[lane]      = (unsigned short)packbf(r0 * inv);
            dst[lane + 64] = (unsigned short)packbf(r1 * inv);
        } else {
            const float* src = proj + (size_t)t * NPROJ + HID_ + 512;
#pragma unroll
            for (int i = 0; i < 4; ++i) {
                int c2 = lane + i * 64;
                vbb[(size_t)t * 256 + c2] = packbf(src[2 * c2]) | (packbf(src[2 * c2 + 1]) << 16);
            }
        }
        return;
    }
    bid -= 5376;
    if (bid < 4096) {   // tcast Wo -> Wot
        tcast_body(Wo, Wot, HID_, bid & 63, bid >> 6, tid, tile);
        return;
    }
    bid -= 4096;
    // ---- idxtopk: t = bid ----
    {
        const int t = bid;
        int* orow = idxout + (size_t)t * TOPK_;
        if (t < TOPK_) { orow[tid] = tid; return; }

        __shared__ float qsh[128];
        __shared__ float wsh[4];
        if (tid < 128) qsh[tid] = proji[(size_t)t * NIDX + tid];
        else if (tid < 132) wsh[tid - 128] = proji[(size_t)t * NIDX + tid];
        __syncthreads();

        const int n = t + 1;
        const int lane = tid & 63, wave = tid >> 6;

        unsigned int key[4];
#pragma unroll
        for (int j = 0; j < 4; ++j) {
            int s = j * 256 + tid;
            if (s < n) {
                const float4* kr = (const float4*)&kib[(size_t)s * DI_];
                float4 k4[8];
#pragma unroll
                for (int d4 = 0; d4 < 8; ++d4) k4[d4] = kr[d4];
                float sc = 0.f;
#pragma unroll
                for (int h = 0; h < HI_; ++h) {
                    float d = 0.f;
#pragma unroll
                    for (int d4 = 0; d4 < 8; ++d4) {
                        const float* qp = &qsh[h * 32 + d4 * 4];
                        d += k4[d4].x * qp[0] + k4[d4].y * qp[1] +
                             k4[d4].z * qp[2] + k4[d4].w * qp[3];
                    }
                    sc += wsh[h] * fmaxf(d, 0.f);
                }
                unsigned int u = __float_as_uint(sc);
                key[j] = (u & 0x80000000u) ? ~u : (u | 0x80000000u);
            } else key[j] = 0u;
        }

        __shared__ int wcnt[2][4];
        unsigned int prefix = 0;
#pragma unroll 1
        for (int b = 31; b >= 0; --b) {
            unsigned int cand = prefix | (1u << b);
            int c = (key[0] >= cand) + (key[1] >= cand) + (key[2] >= cand) + (key[3] >= cand);
#pragma unroll
            for (int o = 32; o > 0; o >>= 1) c += __shfl_xor(c, o);
            if (lane == 0) wcnt[b & 1][wave] = c;
            __syncthreads();
            int total = wcnt[b & 1][0] + wcnt[b & 1][1] + wcnt[b & 1][2] + wcnt[b & 1][3];
            if (total >= TOPK_) prefix = cand;
        }
        const unsigned int T = prefix;

        __shared__ int posc;
        __shared__ int eqtot[4][4];
        __syncthreads();
        {
            int c = (key[0] > T) + (key[1] > T) + (key[2] > T) + (key[3] > T);
#pragma unroll
            for (int o = 32; o > 0; o >>= 1) c += __shfl_xor(c, o);
            if (lane == 0) wcnt[0][wave] = c;
        }
        if (tid == 0) posc = 0;

        int e[4]; int myp[4];
#pragma unroll
        for (int j = 0; j < 4; ++j) {
            e[j] = (key[j] == T) ? 1 : 0;
            unsigned long long m = __ballot(e[j]);
            myp[j] = __popcll(m & ((1ull << lane) - 1ull));
            if (lane == 0) eqtot[j][wave] = __popcll(m);
        }
        __syncthreads();
        const int cntGT = wcnt[0][0] + wcnt[0][1] + wcnt[0][2] + wcnt[0][3];
        const int need = TOPK_ - cntGT;

#pragma unroll
        for (int j = 0; j < 4; ++j)
            if (key[j] > T) {
                int p = atomicAdd(&posc, 1);
                orow[p] = j * 256 + tid;
            }
        int runbase = 0;
#pragma unroll
        for (int j = 0; j < 4; ++j) {
            int wavebase = 0;
#pragma unroll
            for (int w2 = 0; w2 < 4; ++w2) if (w2 < wave) wavebase += eqtot[j][w2];
            int g = runbase + wavebase + myp[j];
            if (e[j] && g < need) orow[cntGT + g] = j * 256 + tid;
            runbase += eqtot[j][0] + eqtot[j][1] + eqtot[j][2] + eqtot[j][3];
        }
    }
}

// ---------------- standalone 64x64 GEMM (Wo output projection) ----------------
__global__ __launch_bounds__(256) void gemm64(const unsigned short* __restrict__ A,
                                              const unsigned short* __restrict__ Bt,
                                              float* __restrict__ C,
                                              int K, int ldc) {
    __shared__ unsigned short As[2 * 64 * 64];
    __shared__ unsigned short Bs[2 * 64 * 64];
    gemm64_body(A, Bt, C, K, ldc, blockIdx.x, blockIdx.y, threadIdx.x, As, Bs);
}

// ---------------- MFMA sparse GQA v7: 32-token dbuf tiles (round-15 proven) ----------------
__global__ __launch_bounds__(256) void attn7(const unsigned short* __restrict__ qbb,
                                             const unsigned short* __restrict__ kbb,
                                             const unsigned short* __restrict__ vbb,
                                             const int* __restrict__ idx,
                                             unsigned short* __restrict__ attnb) {
    const int t = blockIdx.x, n = blockIdx.y;
    const int tid = threadIdx.x, lane = tid & 63, w = tid >> 6;
    const int C = (t + 1 < TOPK_) ? t + 1 : TOPK_;
    const int l15 = lane & 15, lq = lane >> 4;

    __shared__ int sidx[TOPK_];
    __shared__ float sp[4][TOPK_];
    __shared__ float sinv[4];
    __shared__ unsigned short P[4][264];
    __shared__ unsigned short Vs[2][32 * 128];   // 32-token tiles, double-buffered

    sidx[tid] = idx[(size_t)t * TOPK_ + tid];
    __syncthreads();

#define STAGE_V(buf, tau)                                                          \
    {                                                                              \
        _Pragma("unroll")                                                          \
        for (int it = 0; it < 2; ++it) {                                           \
            int c = tid + it * 256;                                                \
            int r = c >> 4, doff = (c & 15) * 8;                                   \
            int gs = doff ^ (((r >> 3) & 3) << 4);                                 \
            GLDS16(&vbb[((size_t)sidx[(tau) * 32 + r] * NKV + n) * DH + gs],       \
                   &Vs[buf][(size_t)c * 8]);                                       \
        }                                                                          \
    }

    STAGE_V(0, 0);   // latency hidden under QK^T + softmax

    const size_t qrow = (size_t)t * NH + n * 4 + (l15 < 4 ? l15 : 3);
    bf16x8 qf[4];
#pragma unroll
    for (int ks = 0; ks < 4; ++ks)
        qf[ks] = *(const bf16x8*)&qbb[qrow * DH + ks * 32 + lq * 8];

    // ---- QK^T: wave w -> token tiles w*4 .. w*4+3 (K gathered direct from L2)
#pragma unroll
    for (int tt = 0; tt < 4; ++tt) {
        const int tile = w * 4 + tt;
        const int tok = tile * 16 + l15;
        const unsigned short* krow = &kbb[((size_t)sidx[tok] * NKV + n) * DH];
        f32x4 acc = {0.f, 0.f, 0.f, 0.f};
        __builtin_amdgcn_s_setprio(1);
#pragma unroll
        for (int ks = 0; ks < 4; ++ks) {
            bf16x8 yf = *(const bf16x8*)&krow[ks * 32 + lq * 8];
            acc = __builtin_amdgcn_mfma_f32_16x16x32_bf16(qf[ks], yf, acc, 0, 0, 0);
        }
        __builtin_amdgcn_s_setprio(0);
        if (lane < 16) {
            int j = tile * 16 + lane;
            bool ok = j < C;
#pragma unroll
            for (int q = 0; q < 4; ++q)
                sp[q][j] = ok ? acc[q] * 0.08838834764831845f : -INFINITY;
        }
    }
    __syncthreads();

    // ---- softmax: wave w -> head w
    {
        float v0 = sp[w][lane], v1 = sp[w][lane + 64],
              v2 = sp[w][lane + 128], v3 = sp[w][lane + 192];
        float m = fmaxf(fmaxf(v0, v1), fmaxf(v2, v3));
#pragma unroll
        for (int o = 32; o > 0; o >>= 1) m = fmaxf(m, __shfl_xor(m, o));
        float e0 = expf(v0 - m), e1 = expf(v1 - m), e2 = expf(v2 - m), e3 = expf(v3 - m);
        float sum = e0 + e1 + e2 + e3;
#pragma unroll
        for (int o = 32; o > 0; o >>= 1) sum += __shfl_xor(sum, o);
        if (lane == 0) sinv[w] = 1.f / sum;
        P[w][lane]       = (unsigned short)packbf(e0);
        P[w][lane + 64]  = (unsigned short)packbf(e1);
        P[w][lane + 128] = (unsigned short)packbf(e2);
        P[w][lane + 192] = (unsigned short)packbf(e3);
    }
    __syncthreads();   // P visible; V tile 0 drained (QK phase covered it)

    // ---- PV: 8 taus of 32 tokens; ping-pong; 1 barrier/tau
    const int prow = (l15 < 4) ? l15 : 3;
    f32x4 pacc[2] = {};
#pragma unroll
    for (int tau = 0; tau < 8; ++tau) {
        const unsigned short* Vb = Vs[tau & 1];
        if (tau < 7) STAGE_V((tau + 1) & 1, tau + 1);
        bf16x8 xf = *(const bf16x8*)&P[prow][tau * 32 + lq * 8];
        const int colr0 = ((2 * w + 0) * 16 + l15) ^ (lq << 4);
        const int colr1 = ((2 * w + 1) * 16 + l15) ^ (lq << 4);
        bf16x8 yf0, yf1;
#pragma unroll
        for (int j = 0; j < 8; ++j) {
            yf0[j] = (short)Vb[(lq * 8 + j) * 128 + colr0];
            yf1[j] = (short)Vb[(lq * 8 + j) * 128 + colr1];
        }
        __builtin_amdgcn_s_setprio(1);
        pacc[0] = __builtin_amdgcn_mfma_f32_16x16x32_bf16(xf, yf0, pacc[0], 0, 0, 0);
        pacc[1] = __builtin_amdgcn_mfma_f32_16x16x32_bf16(xf, yf1, pacc[1], 0, 0, 0);
        __builtin_amdgcn_s_setprio(0);
        __syncthreads();   // drains tau+1 loads + fences buffer reuse
    }
#undef STAGE_V

    if (lane < 16) {
#pragma unroll
        for (int dt = 0; dt < 2; ++dt)
#pragma unroll
            for (int q = 0; q < 4; ++q)
                attnb[(size_t)(t * NH + n * 4 + q) * DH + (2 * w + dt) * 16 + l15] =
                    (unsigned short)packbf(pacc[dt][q] * sinv[q]);
    }
}

// ---------------- launch ----------------
extern "C" void kernel_launch(void* const* d_in, const int* in_sizes, int n_in,
                              void* d_out, int out_size, void* d_ws, size_t ws_size,
                              hipStream_t stream) {
    const float* x    = (const float*)d_in[0];
    const float* cosb = (const float*)d_in[1];
    const float* sinb = (const float*)d_in[2];
    const float* Wq   = (const float*)d_in[3];
    const float* Wk   = (const float*)d_in[4];
    const float* Wv   = (const float*)d_in[5];
    const float* Wo   = (const float*)d_in[6];
    const float* Wqi  = (const float*)d_in[7];
    const float* Wwi  = (const float*)d_in[8];
    const float* Wki  = (const float*)d_in[9];
    float* out = (float*)d_out;

    unsigned short* xb    = (unsigned short*)d_ws;             // 1024*2048 bf16
    unsigned short* WtAll = xb + 2097152;                      // 3072*2048 bf16
    float*  proj  = (float*)(WtAll + 6291456);                 // 1024*3072 f32
    float*  Wi    = proj + 3145728;                            // 2048*164 f32
    float*  proji = Wi + 335872;                               // 1024*164 f32
    float*  kib   = proji + 167936;                            // 1024*32 f32 (4MB slot)
    int*    idxb  = (int*)(kib + 1048576);                     // 1024*256 int
    unsigned short* kbb   = (unsigned short*)(idxb + 262144);  // 1024*512 bf16
    unsigned short* vbb   = kbb + 524288;                      // 1024*512 bf16
    unsigned short* attnb = vbb + 524288;                      // 1024*2048 bf16
    unsigned short* Wot   = WtAll;     // reuse after proj GEMM
    unsigned short* qbb   = xb;        // reuse after proj GEMM
    float* Cpart = (float*)kbb;        // split-K partials, dead before kbb written

    // 1) prep: tcast Wq/Wk/Wv + cast_x + copy_wi
    prep1<<<dim3(8480), dim3(256), 0, stream>>>(x, Wq, Wk, Wv, Wqi, Wwi, Wki, xb, WtAll, Wi);

    // 2) fusedA: bf16 proj GEMM (768, 2-phase pipelined) + fp32 indexer splitk (384)
    fusedA<<<dim3(1152), dim3(256), 0, stream>>>(xb, WtAll, proj, x, Wi, Cpart);

    // 3) reduce split-K partials -> proji, kib
    reduce_k<<<dim3((T_ * NIDX + 255) / 256), dim3(256), 0, stream>>>(Cpart, proji, kib, T_ * NIDX);

    // 4) fusedB: rope/rms q,k + v cast (5376) + tcast Wo (4096) + idxtopk (1024)
    fusedB<<<dim3(10496), dim3(256), 0, stream>>>(proj, cosb, sinb, qbb, kbb, (unsigned int*)vbb,
                                                  Wo, Wot, proji, kib, idxb);

    // 5) sparse attention (32-token dbuf tiles)
    attn7<<<dim3(T_, NKV), dim3(256), 0, stream>>>(qbb, kbb, vbb, idxb, attnb);

    // 6) output projection (2-phase pipelined)
    gemm64<<<dim3(HID_ / 64, T_ / 64), dim3(256), 0, stream>>>(attnb, Wot, out, HID_, HID_);
}

// Round 17
// 151.145 us; speedup vs baseline: 1.1293x; 1.1209x over previous
//
#include <hip/hip_runtime.h>
#include <hip/hip_bf16.h>
#include <math.h>

#define T_    1024
#define HID_  2048
#define NH    16
#define NKV   4
#define DH    128
#define TOPK_ 256
#define HI_   4
#define DI_   32
#define NPROJ 3072          // q(2048) + k(512) + v(512)
#define NIDX  164           // qi(128) + wi(4) + ki(32)
#define KSPLIT 8
#define KCHUNK 256

#ifndef INFINITY
#define INFINITY (__builtin_inff())
#endif

typedef __attribute__((ext_vector_type(8))) short bf16x8;
typedef __attribute__((ext_vector_type(4))) float f32x4;

__device__ inline unsigned int packbf(float f) {   // RNE f32->bf16 (bits in low 16)
    unsigned int u = __float_as_uint(f);
    return (u + 0x7fffu + ((u >> 16) & 1u)) >> 16;
}

#define GLDS16(g, l) __builtin_amdgcn_global_load_lds( \
    (const __attribute__((address_space(1))) void*)(g), \
    (__attribute__((address_space(3))) void*)(l), 16, 0, 0)

// ---------------- shared device bodies ----------------
__device__ inline void tcast_body(const float* __restrict__ W, unsigned short* __restrict__ Wt,
                                  int N, int bx, int by, int tid, float (*tile)[33]) {
    const int n0 = bx * 32, k0 = by * 32;
    const int tx = tid & 31, ty = tid >> 5;
#pragma unroll
    for (int i = 0; i < 4; ++i)
        tile[ty + i * 8][tx] = W[(size_t)(k0 + ty + i * 8) * N + (n0 + tx)];
    __syncthreads();
#pragma unroll
    for (int i = 0; i < 4; ++i) {
        int n = n0 + ty + i * 8;
        Wt[(size_t)n * HID_ + k0 + tx] = (unsigned short)packbf(tile[tx][ty + i * 8]);
    }
}

// 64x64 bf16 MFMA GEMM body, BK=64, swizzled staging + 2-phase pipeline (round-16 proven)
__device__ inline void gemm64_body(const unsigned short* __restrict__ A,
                                   const unsigned short* __restrict__ Bt,
                                   float* __restrict__ C, int K, int ldc,
                                   int bx, int by, int tid,
                                   unsigned short* As, unsigned short* Bs) {
    const int lane = tid & 63, w = tid >> 6;
    const int wr = w >> 1, wc = w & 1;
    const int brow = by * 64, bcol = bx * 64;
    const int l15 = lane & 15, lq = lane >> 4;

    f32x4 acc[2][2] = {};

    const int srow = tid >> 3;
    const int gsrc = ((tid & 7) ^ (srow & 7)) * 8;
    const unsigned short* ga  = A  + (size_t)(brow + srow) * K + gsrc;
    const unsigned short* ga2 = ga + (size_t)32 * K;
    const unsigned short* gb  = Bt + (size_t)(bcol + srow) * K + gsrc;
    const unsigned short* gb2 = gb + (size_t)32 * K;
    const int lo1 = tid * 8, lo2 = (tid + 256) * 8;

    GLDS16(ga,  &As[lo1]);
    GLDS16(ga2, &As[lo2]);
    GLDS16(gb,  &Bs[lo1]);
    GLDS16(gb2, &Bs[lo2]);
    __syncthreads();

    const int NT = K >> 6;
    for (int kt = 0; kt < NT; ++kt) {
        const int cur = (kt & 1) * 4096;
        if (kt + 1 < NT) {
            const int nxt = ((kt + 1) & 1) * 4096;
            const int k0 = (kt + 1) << 6;
            GLDS16(ga + k0,  &As[nxt + lo1]);
            GLDS16(ga2 + k0, &As[nxt + lo2]);
            GLDS16(gb + k0,  &Bs[nxt + lo1]);
            GLDS16(gb2 + k0, &Bs[nxt + lo2]);
        }
        const unsigned short* Ac = &As[cur];
        const unsigned short* Bc = &Bs[cur];
        bf16x8 fa[2][2], fb[2][2];
#pragma unroll
        for (int m = 0; m < 2; ++m)
#pragma unroll
            for (int kk = 0; kk < 2; ++kk) {
                int row = wr * 32 + m * 16 + l15;
                fa[m][kk] = *(const bf16x8*)&Ac[row * 64 + (((kk * 4 + lq) ^ (l15 & 7)) * 8)];
            }
#pragma unroll
        for (int nn = 0; nn < 2; ++nn)
#pragma unroll
            for (int kk = 0; kk < 2; ++kk) {
                int row = wc * 32 + nn * 16 + l15;
                fb[nn][kk] = *(const bf16x8*)&Bc[row * 64 + (((kk * 4 + lq) ^ (l15 & 7)) * 8)];
            }
#pragma unroll
        for (int kk = 0; kk < 2; ++kk)
#pragma unroll
            for (int m = 0; m < 2; ++m)
#pragma unroll
                for (int nn = 0; nn < 2; ++nn)
                    acc[m][nn] = __builtin_amdgcn_mfma_f32_16x16x32_bf16(fa[m][kk], fb[nn][kk], acc[m][nn], 0, 0, 0);
        __syncthreads();
    }
#pragma unroll
    for (int m = 0; m < 2; ++m)
#pragma unroll
        for (int nn = 0; nn < 2; ++nn)
#pragma unroll
            for (int q = 0; q < 4; ++q) {
                int row = brow + wr * 32 + m * 16 + lq * 4 + q;
                int col = bcol + wc * 32 + nn * 16 + l15;
                C[(size_t)row * ldc + col] = acc[m][nn][q];
            }
}

// ---------------- prep1: tcast Wq/Wk/Wv + cast_x + copy_wi ----------------
__global__ __launch_bounds__(256) void prep1(const float* __restrict__ x,
                                             const float* __restrict__ Wq,
                                             const float* __restrict__ Wk,
                                             const float* __restrict__ Wv,
                                             const float* __restrict__ Wqi,
                                             const float* __restrict__ Wwi,
                                             const float* __restrict__ Wki,
                                             unsigned short* __restrict__ xb,
                                             unsigned short* __restrict__ WtAll,
                                             float* __restrict__ Wi) {
    __shared__ float tile[32][33];
    int bid = blockIdx.x;
    const int tid = threadIdx.x;
    if (bid < 4096) { tcast_body(Wq, WtAll, HID_, bid & 63, bid >> 6, tid, tile); return; }
    bid -= 4096;
    if (bid < 1024) { tcast_body(Wk, WtAll + (size_t)2048 * HID_, 512, bid & 15, bid >> 4, tid, tile); return; }
    bid -= 1024;
    if (bid < 1024) { tcast_body(Wv, WtAll + (size_t)2560 * HID_, 512, bid & 15, bid >> 4, tid, tile); return; }
    bid -= 1024;
    if (bid < 1024) {
        int e = bid * 256 + tid;
        const float4* p = (const float4*)(x + (size_t)e * 8);
        float4 a = p[0], b = p[1];
        uint4 r;
        r.x = packbf(a.x) | (packbf(a.y) << 16);
        r.y = packbf(a.z) | (packbf(a.w) << 16);
        r.z = packbf(b.x) | (packbf(b.y) << 16);
        r.w = packbf(b.z) | (packbf(b.w) << 16);
        *(uint4*)(xb + (size_t)e * 8) = r;
        return;
    }
    bid -= 1024;
    {
        int e = bid * 256 + tid;
        if (e >= HID_ * NIDX) return;
        int k = e / NIDX, c = e - k * NIDX;
        float v;
        if (c < 128) v = Wqi[(size_t)k * 128 + c];
        else if (c < 132) v = Wwi[(size_t)k * 4 + (c - 128)];
        else v = Wki[(size_t)k * 32 + (c - 132)];
        Wi[e] = v;
    }
}

// ---------------- fusedA: bf16 proj GEMM (768) + fp32 splitk (384), LDS union ----------------
__global__ __launch_bounds__(256) void fusedA(const unsigned short* __restrict__ xb,
                                              const unsigned short* __restrict__ WtAll,
                                              float* __restrict__ proj,
                                              const float* __restrict__ x,
                                              const float* __restrict__ Wi,
                                              float* __restrict__ Cpart) {
    __shared__ __align__(16) char smem[64 * 64 * 2 * 2 * 2];   // 32768 B, unioned
    const int tid = threadIdx.x;
    int bid = blockIdx.x;

    if (bid < 768) {
        unsigned short* As = (unsigned short*)smem;
        unsigned short* Bs = As + 8192;
        gemm64_body(xb, WtAll, proj, HID_, NPROJ, bid % 48, bid / 48, tid, As, Bs);
        return;
    }
    float (*As2)[68] = (float(*)[68])smem;
    float (*Bs2)[68] = As2 + 16;
    int s = bid - 768;
    const int bx = s % 3, by = (s / 3) % 16, z = s / 48;
    const int tx = tid & 15, ty = tid >> 4;
    const int brow = by * 64, bcol = bx * 64;
    const int kbeg = z * KCHUNK, kend = kbeg + KCHUNK;
    const int M = T_, N = NIDX, K = HID_;

    const int ar = tid >> 2, ac4 = (tid & 3) * 4;
    const int br = tid >> 4, bc4 = (tid & 15) * 4;

    float acc[4][4];
#pragma unroll
    for (int i = 0; i < 4; ++i)
#pragma unroll
        for (int j = 0; j < 4; ++j) acc[i][j] = 0.f;

    for (int k0 = kbeg; k0 < kend; k0 += 16) {
        float4 va = *(const float4*)&x[(size_t)(brow + ar) * K + k0 + ac4];
        float4 vb;
        int col = bcol + bc4;
        if (col <= N - 4) vb = *(const float4*)&Wi[(size_t)(k0 + br) * N + col];
        else vb = (float4){0.f, 0.f, 0.f, 0.f};
        As2[ac4 + 0][ar] = va.x;
        As2[ac4 + 1][ar] = va.y;
        As2[ac4 + 2][ar] = va.z;
        As2[ac4 + 3][ar] = va.w;
        *(float4*)&Bs2[br][bc4] = vb;
        __syncthreads();
#pragma unroll
        for (int kk = 0; kk < 16; ++kk) {
            float4 a4 = *(const float4*)&As2[kk][ty * 4];
            float4 b4 = *(const float4*)&Bs2[kk][tx * 4];
            float a[4] = {a4.x, a4.y, a4.z, a4.w};
            float b[4] = {b4.x, b4.y, b4.z, b4.w};
#pragma unroll
            for (int i = 0; i < 4; ++i)
#pragma unroll
                for (int j = 0; j < 4; ++j) acc[i][j] += a[i] * b[j];
        }
        __syncthreads();
    }
#pragma unroll
    for (int i = 0; i < 4; ++i) {
        int r = brow + ty * 4 + i;
#pragma unroll
        for (int j = 0; j < 4; ++j) {
            int c = bcol + tx * 4 + j;
            if (c < N) Cpart[((size_t)z * M + r) * N + c] = acc[i][j];
        }
    }
}

// ---------------- reduce split-K partials; also emit dense kib ----------------
__global__ __launch_bounds__(256) void reduce_k(const float* __restrict__ Cpart,
                                                float* __restrict__ Cout,
                                                float* __restrict__ kib, int MN) {
    int e = blockIdx.x * 256 + threadIdx.x;
    if (e >= MN) return;
    float s = 0.f;
#pragma unroll
    for (int z = 0; z < KSPLIT; ++z) s += Cpart[(size_t)z * MN + e];
    Cout[e] = s;
    int t = e / NIDX, c = e - t * NIDX;
    if (c >= 132) kib[(size_t)t * DI_ + (c - 132)] = s;
}

// ---------------- fusedB v2: idxtopk FIRST (1024) + rope (5376) + tcast Wo (4096) ----------------
__global__ __launch_bounds__(256) void fusedB(const float* __restrict__ proj,
                                              const float* __restrict__ cosb,
                                              const float* __restrict__ sinb,
                                              unsigned short* __restrict__ qbb,
                                              unsigned short* __restrict__ kbb,
                                              unsigned int* __restrict__ vbb,
                                              const float* __restrict__ Wo,
                                              unsigned short* __restrict__ Wot,
                                              const float* __restrict__ proji,
                                              const float* __restrict__ kib,
                                              int* __restrict__ idxout) {
    __shared__ float tile[32][33];
    const int tid = threadIdx.x;
    int bid = blockIdx.x;

    if (bid < 1024) {
        // ---- idxtopk: t = bid (long-pole blocks scheduled first) ----
        const int t = bid;
        int* orow = idxout + (size_t)t * TOPK_;
        if (t < TOPK_) { orow[tid] = tid; return; }

        __shared__ float qsh[128];
        __shared__ float wsh[4];
        if (tid < 128) qsh[tid] = proji[(size_t)t * NIDX + tid];
        else if (tid < 132) wsh[tid - 128] = proji[(size_t)t * NIDX + tid];
        __syncthreads();

        const int n = t + 1;
        const int lane = tid & 63, wave = tid >> 6;

        unsigned int key[4];
#pragma unroll
        for (int j = 0; j < 4; ++j) {
            int s = j * 256 + tid;
            if (s < n) {
                const float4* kr = (const float4*)&kib[(size_t)s * DI_];
                float4 k4[8];
#pragma unroll
                for (int d4 = 0; d4 < 8; ++d4) k4[d4] = kr[d4];
                float sc = 0.f;
#pragma unroll
                for (int h = 0; h < HI_; ++h) {
                    float d = 0.f;
#pragma unroll
                    for (int d4 = 0; d4 < 8; ++d4) {
                        const float* qp = &qsh[h * 32 + d4 * 4];
                        d += k4[d4].x * qp[0] + k4[d4].y * qp[1] +
                             k4[d4].z * qp[2] + k4[d4].w * qp[3];
                    }
                    sc += wsh[h] * fmaxf(d, 0.f);
                }
                unsigned int u = __float_as_uint(sc);
                key[j] = (u & 0x80000000u) ? ~u : (u | 0x80000000u);
            } else key[j] = 0u;
        }

        __shared__ int wcnt[2][4];
        unsigned int prefix = 0;
#pragma unroll 1
        for (int b = 31; b >= 0; --b) {
            unsigned int cand = prefix | (1u << b);
            int c = (key[0] >= cand) + (key[1] >= cand) + (key[2] >= cand) + (key[3] >= cand);
#pragma unroll
            for (int o = 32; o > 0; o >>= 1) c += __shfl_xor(c, o);
            if (lane == 0) wcnt[b & 1][wave] = c;
            __syncthreads();
            int total = wcnt[b & 1][0] + wcnt[b & 1][1] + wcnt[b & 1][2] + wcnt[b & 1][3];
            if (total >= TOPK_) prefix = cand;
        }
        const unsigned int T = prefix;

        __shared__ int posc;
        __shared__ int eqtot[4][4];
        __syncthreads();
        {
            int c = (key[0] > T) + (key[1] > T) + (key[2] > T) + (key[3] > T);
#pragma unroll
            for (int o = 32; o > 0; o >>= 1) c += __shfl_xor(c, o);
            if (lane == 0) wcnt[0][wave] = c;
        }
        if (tid == 0) posc = 0;

        int e[4]; int myp[4];
#pragma unroll
        for (int j = 0; j < 4; ++j) {
            e[j] = (key[j] == T) ? 1 : 0;
            unsigned long long m = __ballot(e[j]);
            myp[j] = __popcll(m & ((1ull << lane) - 1ull));
            if (lane == 0) eqtot[j][wave] = __popcll(m);
        }
        __syncthreads();
        const int cntGT = wcnt[0][0] + wcnt[0][1] + wcnt[0][2] + wcnt[0][3];
        const int need = TOPK_ - cntGT;

#pragma unroll
        for (int j = 0; j < 4; ++j)
            if (key[j] > T) {
                int p = atomicAdd(&posc, 1);
                orow[p] = j * 256 + tid;
            }
        int runbase = 0;
#pragma unroll
        for (int j = 0; j < 4; ++j) {
            int wavebase = 0;
#pragma unroll
            for (int w2 = 0; w2 < 4; ++w2) if (w2 < wave) wavebase += eqtot[j][w2];
            int g = runbase + wavebase + myp[j];
            if (e[j] && g < need) orow[cntGT + g] = j * 256 + tid;
            runbase += eqtot[j][0] + eqtot[j][1] + eqtot[j][2] + eqtot[j][3];
        }
        return;
    }
    bid -= 1024;
    if (bid < 5376) {   // rope units: u = bid*4 + wave, u = t*21 + h
        const int w = tid >> 6, lane = tid & 63;
        const int u = bid * 4 + w;
        const int t = u / 21, h = u - t * 21;
        if (h < 20) {
            const float* row;
            unsigned short* dst;
            if (h < 16) { row = proj + (size_t)t * NPROJ + h * DH;               dst = qbb + ((size_t)t * NH + h) * DH; }
            else        { row = proj + (size_t)t * NPROJ + HID_ + (h - 16) * DH; dst = kbb + ((size_t)t * NKV + (h - 16)) * DH; }
            float a = row[lane], b = row[lane + 64];
            float c0 = cosb[t * DH + lane],      s0 = sinb[t * DH + lane];
            float c1 = cosb[t * DH + lane + 64], s1 = sinb[t * DH + lane + 64];
            float r0 = a * c0 - b * s0;
            float r1 = b * c1 + a * s1;
            float ss = r0 * r0 + r1 * r1;
#pragma unroll
            for (int o = 32; o > 0; o >>= 1) ss += __shfl_xor(ss, o);
            float inv = rsqrtf(ss * (1.0f / 128.0f) + 1.1920929e-07f);
            dst[lane]      = (unsigned short)packbf(r0 * inv);
            dst[lane + 64] = (unsigned short)packbf(r1 * inv);
        } else {
            const float* src = proj + (size_t)t * NPROJ + HID_ + 512;
#pragma unroll
            for (int i = 0; i < 4; ++i) {
                int c2 = lane + i * 64;
                vbb[(size_t)t * 256 + c2] = packbf(src[2 * c2]) | (packbf(src[2 * c2 + 1]) << 16);
            }
        }
        return;
    }
    bid -= 5376;
    // tcast Wo -> Wot (last 4096)
    tcast_body(Wo, Wot, HID_, bid & 63, bid >> 6, tid, tile);
}

// ---------------- standalone 64x64 GEMM (Wo output projection) ----------------
__global__ __launch_bounds__(256) void gemm64(const unsigned short* __restrict__ A,
                                              const unsigned short* __restrict__ Bt,
                                              float* __restrict__ C,
                                              int K, int ldc) {
    __shared__ unsigned short As[2 * 64 * 64];
    __shared__ unsigned short Bs[2 * 64 * 64];
    gemm64_body(A, Bt, C, K, ldc, blockIdx.x, blockIdx.y, threadIdx.x, As, Bs);
}

// ---------------- MFMA sparse GQA v8: round-15 structure + QK 1-tile K lookahead ----------------
__global__ __launch_bounds__(256) void attn8(const unsigned short* __restrict__ qbb,
                                             const unsigned short* __restrict__ kbb,
                                             const unsigned short* __restrict__ vbb,
                                             const int* __restrict__ idx,
                                             unsigned short* __restrict__ attnb) {
    const int t = blockIdx.x, n = blockIdx.y;
    const int tid = threadIdx.x, lane = tid & 63, w = tid >> 6;
    const int C = (t + 1 < TOPK_) ? t + 1 : TOPK_;
    const int l15 = lane & 15, lq = lane >> 4;

    __shared__ int sidx[TOPK_];
    __shared__ float sp[4][TOPK_];
    __shared__ float sinv[4];
    __shared__ unsigned short P[4][264];
    __shared__ unsigned short Vs[2][32 * 128];   // 32-token tiles, double-buffered

    sidx[tid] = idx[(size_t)t * TOPK_ + tid];
    __syncthreads();

#define STAGE_V(buf, tau)                                                          \
    {                                                                              \
        _Pragma("unroll")                                                          \
        for (int it = 0; it < 2; ++it) {                                           \
            int c = tid + it * 256;                                                \
            int r = c >> 4, doff = (c & 15) * 8;                                   \
            int gs = doff ^ (((r >> 3) & 3) << 4);                                 \
            GLDS16(&vbb[((size_t)sidx[(tau) * 32 + r] * NKV + n) * DH + gs],       \
                   &Vs[buf][(size_t)c * 8]);                                       \
        }                                                                          \
    }

    STAGE_V(0, 0);   // latency hidden under QK^T + softmax

    const size_t qrow = (size_t)t * NH + n * 4 + (l15 < 4 ? l15 : 3);
    bf16x8 qf[4];
#pragma unroll
    for (int ks = 0; ks < 4; ++ks)
        qf[ks] = *(const bf16x8*)&qbb[qrow * DH + ks * 32 + lq * 8];

    // ---- QK^T with 1-tile K lookahead: load tile tt+1's fragments during tile tt's MFMAs
    bf16x8 kf[4], kf2[4];
    {
        const unsigned short* kr0 = &kbb[((size_t)sidx[(w * 4) * 16 + l15] * NKV + n) * DH];
#pragma unroll
        for (int ks = 0; ks < 4; ++ks) kf[ks] = *(const bf16x8*)&kr0[ks * 32 + lq * 8];
    }
#pragma unroll
    for (int tt = 0; tt < 4; ++tt) {
        if (tt < 3) {
            const unsigned short* krn =
                &kbb[((size_t)sidx[(w * 4 + tt + 1) * 16 + l15] * NKV + n) * DH];
#pragma unroll
            for (int ks = 0; ks < 4; ++ks) kf2[ks] = *(const bf16x8*)&krn[ks * 32 + lq * 8];
        }
        f32x4 acc = {0.f, 0.f, 0.f, 0.f};
        __builtin_amdgcn_s_setprio(1);
#pragma unroll
        for (int ks = 0; ks < 4; ++ks)
            acc = __builtin_amdgcn_mfma_f32_16x16x32_bf16(qf[ks], kf[ks], acc, 0, 0, 0);
        __builtin_amdgcn_s_setprio(0);
        if (lane < 16) {
            int j = (w * 4 + tt) * 16 + lane;
            bool ok = j < C;
#pragma unroll
            for (int q = 0; q < 4; ++q)
                sp[q][j] = ok ? acc[q] * 0.08838834764831845f : -INFINITY;
        }
#pragma unroll
        for (int ks = 0; ks < 4; ++ks) kf[ks] = kf2[ks];
    }
    __syncthreads();

    // ---- softmax: wave w -> head w
    {
        float v0 = sp[w][lane], v1 = sp[w][lane + 64],
              v2 = sp[w][lane + 128], v3 = sp[w][lane + 192];
        float m = fmaxf(fmaxf(v0, v1), fmaxf(v2, v3));
#pragma unroll
        for (int o = 32; o > 0; o >>= 1) m = fmaxf(m, __shfl_xor(m, o));
        float e0 = expf(v0 - m), e1 = expf(v1 - m), e2 = expf(v2 - m), e3 = expf(v3 - m);
        float sum = e0 + e1 + e2 + e3;
#pragma unroll
        for (int o = 32; o > 0; o >>= 1) sum += __shfl_xor(sum, o);
        if (lane == 0) sinv[w] = 1.f / sum;
        P[w][lane]       = (unsigned short)packbf(e0);
        P[w][lane + 64]  = (unsigned short)packbf(e1);
        P[w][lane + 128] = (unsigned short)packbf(e2);
        P[w][lane + 192] = (unsigned short)packbf(e3);
    }
    __syncthreads();   // P visible; V tile 0 drained (QK phase covered it)

    // ---- PV: 8 taus of 32 tokens; ping-pong; 1 barrier/tau
    const int prow = (l15 < 4) ? l15 : 3;
    f32x4 pacc[2] = {};
#pragma unroll
    for (int tau = 0; tau < 8; ++tau) {
        const unsigned short* Vb = Vs[tau & 1];
        if (tau < 7) STAGE_V((tau + 1) & 1, tau + 1);
        bf16x8 xf = *(const bf16x8*)&P[prow][tau * 32 + lq * 8];
        const int colr0 = ((2 * w + 0) * 16 + l15) ^ (lq << 4);
        const int colr1 = ((2 * w + 1) * 16 + l15) ^ (lq << 4);
        bf16x8 yf0, yf1;
#pragma unroll
        for (int j = 0; j < 8; ++j) {
            yf0[j] = (short)Vb[(lq * 8 + j) * 128 + colr0];
            yf1[j] = (short)Vb[(lq * 8 + j) * 128 + colr1];
        }
        __builtin_amdgcn_s_setprio(1);
        pacc[0] = __builtin_amdgcn_mfma_f32_16x16x32_bf16(xf, yf0, pacc[0], 0, 0, 0);
        pacc[1] = __builtin_amdgcn_mfma_f32_16x16x32_bf16(xf, yf1, pacc[1], 0, 0, 0);
        __builtin_amdgcn_s_setprio(0);
        __syncthreads();   // drains tau+1 loads + fences buffer reuse
    }
#undef STAGE_V

    if (lane < 16) {
#pragma unroll
        for (int dt = 0; dt < 2; ++dt)
#pragma unroll
            for (int q = 0; q < 4; ++q)
                attnb[(size_t)(t * NH + n * 4 + q) * DH + (2 * w + dt) * 16 + l15] =
                    (unsigned short)packbf(pacc[dt][q] * sinv[q]);
    }
}

// ---------------- launch ----------------
extern "C" void kernel_launch(void* const* d_in, const int* in_sizes, int n_in,
                              void* d_out, int out_size, void* d_ws, size_t ws_size,
                              hipStream_t stream) {
    const float* x    = (const float*)d_in[0];
    const float* cosb = (const float*)d_in[1];
    const float* sinb = (const float*)d_in[2];
    const float* Wq   = (const float*)d_in[3];
    const float* Wk   = (const float*)d_in[4];
    const float* Wv   = (const float*)d_in[5];
    const float* Wo   = (const float*)d_in[6];
    const float* Wqi  = (const float*)d_in[7];
    const float* Wwi  = (const float*)d_in[8];
    const float* Wki  = (const float*)d_in[9];
    float* out = (float*)d_out;

    unsigned short* xb    = (unsigned short*)d_ws;             // 1024*2048 bf16
    unsigned short* WtAll = xb + 2097152;                      // 3072*2048 bf16
    float*  proj  = (float*)(WtAll + 6291456);                 // 1024*3072 f32
    float*  Wi    = proj + 3145728;                            // 2048*164 f32
    float*  proji = Wi + 335872;                               // 1024*164 f32
    float*  kib   = proji + 167936;                            // 1024*32 f32 (4MB slot)
    int*    idxb  = (int*)(kib + 1048576);                     // 1024*256 int
    unsigned short* kbb   = (unsigned short*)(idxb + 262144);  // 1024*512 bf16
    unsigned short* vbb   = kbb + 524288;                      // 1024*512 bf16
    unsigned short* attnb = vbb + 524288;                      // 1024*2048 bf16
    unsigned short* Wot   = WtAll;     // reuse after proj GEMM
    unsigned short* qbb   = xb;        // reuse after proj GEMM
    float* Cpart = (float*)kbb;        // split-K partials, dead before kbb written

    // 1) prep: tcast Wq/Wk/Wv + cast_x + copy_wi
    prep1<<<dim3(8480), dim3(256), 0, stream>>>(x, Wq, Wk, Wv, Wqi, Wwi, Wki, xb, WtAll, Wi);

    // 2) fusedA: bf16 proj GEMM (768, pipelined) + fp32 indexer splitk (384)
    fusedA<<<dim3(1152), dim3(256), 0, stream>>>(xb, WtAll, proj, x, Wi, Cpart);

    // 3) reduce split-K partials -> proji, kib
    reduce_k<<<dim3((T_ * NIDX + 255) / 256), dim3(256), 0, stream>>>(Cpart, proji, kib, T_ * NIDX);

    // 4) fusedB: idxtopk (first, long-pole) + rope/rms/vcast + tcast Wo
    fusedB<<<dim3(10496), dim3(256), 0, stream>>>(proj, cosb, sinb, qbb, kbb, (unsigned int*)vbb,
                                                  Wo, Wot, proji, kib, idxb);

    // 5) sparse attention (QK lookahead + 32-token dbuf PV)
    attn8<<<dim3(T_, NKV), dim3(256), 0, stream>>>(qbb, kbb, vbb, idxb, attnb);

    // 6) output projection (pipelined)
    gemm64<<<dim3(HID_ / 64, T_ / 64), dim3(256), 0, stream>>>(attnb, Wot, out, HID_, HID_);
}